// Round 3
// baseline (152.291 us; speedup 1.0000x reference)
//
#include <hip/hip_runtime.h>

// LinearGaussianTree, MI355X. 8192 independent rows; per row a 4095-node
// binary tree: s_i = w_i * s_parent + (1-w_i)*SCALE*noise_i.
// Outputs fp32 flat: samples (8192x4095), ms (8192x4094), scales (8192x4094),
// columns in reverse level order; root = samples col 4094.
//
// Column identity: parent_col = (child_col >> 1) + 2048.
// Block = 4 consecutive rows. 4*4095 = 16380 and 4*4094 = 16376 are both
// multiples of 4 => per-block flat output ranges are 16B-aligned: all global
// stores are aligned dwordx4 with no head/tail peel. Samples staged in LDS in
// flat output order (65,520 B) so write-back is aligned ds_read_b128 ->
// global_store_dwordx4. ms recomputed from staged parent (1 mul); scales is a
// table broadcast.

constexpr int   kDepth  = 12;
constexpr int   kRows   = 8192;
constexpr float kScale  = 0.1f;
constexpr int   kBlkPre = 256;
constexpr int   kBlk    = 1024;   // main kernel threads
constexpr int   kG      = 4;      // rows per block
constexpr int   kSampB  = kG * 4095;  // 16380 floats staged per block
constexpr int   kRestB  = kG * 4094;  // 16376

// Column-ordered sigmoid tables (zero-init BSS; rewritten every launch).
__device__ __align__(16) float g_wcol[4096];
__device__ __align__(16) float g_sccol[4096];

__global__ __launch_bounds__(kBlkPre) void lgt_precompute(
    const float* __restrict__ weights)
{
    int t = blockIdx.x * kBlkPre + threadIdx.x;   // tree index 0..4093
    if (t < 4094) {
        int d = 31 - __clz(t + 2);                // level of node t
        int c = t + 4098 - 3 * (1 << d);          // output column
        float w = 1.0f / (1.0f + __expf(-weights[t]));
        g_wcol[c]  = w;
        g_sccol[c] = (1.0f - w) * kScale;
    }
}

__global__ __launch_bounds__(kBlk) void lgt_main(
    const float* __restrict__ noise_root,
    const float* __restrict__ noise_rest,
    float* __restrict__ samples,
    float* __restrict__ ms,
    float* __restrict__ scales)
{
    // Flat output order: s[r*4095 + col], r in [0,4).
    __shared__ float s[kSampB];

    const int blk  = blockIdx.x;
    const int tid  = threadIdx.x;
    const int row0 = blk << 2;

    // ---- phase 1: build 4 trees in LDS ----
    if (tid < 4) {
        s[tid * 4095 + 4094] = noise_root[row0 + tid];   // IN_SCALE == 1.0
    }
    __syncthreads();

    if (tid < 8) {                       // level 1: cols 4092/4093, tree idx 0/1
        const int r = tid >> 1, i = tid & 1;
        const int c = 4092 + i;
        const float par = s[r * 4095 + 4094];
        s[r * 4095 + c] =
            fmaf(g_sccol[c], noise_rest[(size_t)(row0 + r) * 4094 + i],
                 g_wcol[c] * par);
    }
    __syncthreads();

    int off = 2;                                  // off_d = 2^d - 2
    for (int d = 2; d < kDepth; ++d) {
        const int n       = 1 << d;
        const int colbase = 4096 - (n << 1);      // ≡ 0 (mod 4)
        const int qshift  = d - 2;                // log2(n/4)
        const int qmask   = (n >> 2) - 1;
        for (int t = tid; t < n; t += kBlk) {     // n tasks = 4 rows * n/4 quads
            const int r  = t >> qshift;
            const int i0 = (t & qmask) << 2;
            const int c  = colbase + i0;          // ≡ 0 (mod 4)
            const int lb = r * 4095;
            const float4 w4  = *(const float4*)(g_wcol  + c);
            const float4 sc4 = *(const float4*)(g_sccol + c);
            const float* nrp = noise_rest + (size_t)(row0 + r) * 4094 + off + i0;
            const float2 nz0 = *(const float2*)(nrp);      // off+i0 even
            const float2 nz1 = *(const float2*)(nrp + 2);
            const int p = lb + (c >> 1) + 2048;   // parent (col-order identity)
            const float p0 = s[p], p1 = s[p + 1];
            s[lb + c]     = fmaf(sc4.x, nz0.x, w4.x * p0);
            s[lb + c + 1] = fmaf(sc4.y, nz0.y, w4.y * p0);
            s[lb + c + 2] = fmaf(sc4.z, nz1.x, w4.z * p1);
            s[lb + c + 3] = fmaf(sc4.w, nz1.y, w4.w * p1);
        }
        __syncthreads();
        off += n;
    }

    // ---- phase 2a: samples write-back (flat copy, all aligned) ----
    {
        float* __restrict__ sb = samples + (size_t)blk * kSampB;
        for (int k = tid; k < (kSampB >> 2); k += kBlk) {
            const int j = k << 2;
            const float4 v = *(const float4*)(s + j);   // ds_read_b128, aligned
            *(float4*)(sb + j) = v;                     // aligned dwordx4
        }
    }

    // ---- phase 2bc: ms + scales (aligned dwordx4, same-row fast path) ----
    {
        float* __restrict__ mb = ms     + (size_t)blk * kRestB;
        float* __restrict__ cb = scales + (size_t)blk * kRestB;
        for (int k = tid; k < (kRestB >> 2); k += kBlk) {
            const int j  = k << 2;
            const int r0 = (j >= 4094) + (j >= 8188) + (j >= 12282);
            const int r3 = ((j + 3) >= 4094) + ((j + 3) >= 8188) + ((j + 3) >= 12282);
            float4 mv, cv;
            if (r0 == r3) {                       // 4091 of 4094 chunks
                const int c = j - r0 * 4094;      // even -> float2 aligned
                const float2 wa = *(const float2*)(g_wcol  + c);
                const float2 wb = *(const float2*)(g_wcol  + c + 2);
                const float2 ca = *(const float2*)(g_sccol + c);
                const float2 cb2= *(const float2*)(g_sccol + c + 2);
                const int p = r0 * 4095 + (c >> 1) + 2048;
                const float p0 = s[p], p1 = s[p + 1];
                mv.x = wa.x * p0; mv.y = wa.y * p0;
                mv.z = wb.x * p1; mv.w = wb.y * p1;
                cv.x = ca.x; cv.y = ca.y; cv.z = cb2.x; cv.w = cb2.y;
            } else {                              // row-boundary chunk
                float* mvp = (float*)&mv;
                float* cvp = (float*)&cv;
                #pragma unroll
                for (int e = 0; e < 4; ++e) {
                    const int je = j + e;
                    const int r  = (je >= 4094) + (je >= 8188) + (je >= 12282);
                    const int c  = je - r * 4094;
                    mvp[e] = g_wcol[c] * s[r * 4095 + (c >> 1) + 2048];
                    cvp[e] = g_sccol[c];
                }
            }
            *(float4*)(mb + j) = mv;
            *(float4*)(cb + j) = cv;
        }
    }
}

extern "C" void kernel_launch(void* const* d_in, const int* in_sizes, int n_in,
                              void* d_out, int out_size, void* d_ws, size_t ws_size,
                              hipStream_t stream)
{
    const float* weights    = (const float*)d_in[0];
    const float* noise_root = (const float*)d_in[1];
    const float* noise_rest = (const float*)d_in[2];

    float* out     = (float*)d_out;
    float* samples = out;
    float* ms      = samples + (size_t)kRows * 4095;
    float* scales  = ms      + (size_t)kRows * 4094;

    lgt_precompute<<<(4094 + kBlkPre - 1) / kBlkPre, kBlkPre, 0, stream>>>(weights);
    lgt_main<<<kRows / kG, kBlk, 0, stream>>>(noise_root, noise_rest,
                                              samples, ms, scales);
}

// Round 4
// 121.940 us; speedup vs baseline: 1.2489x; 1.2489x over previous
//
#include <hip/hip_runtime.h>

// LinearGaussianTree, MI355X. 8192 independent rows; per row a 4095-node
// binary tree: s_i = w_i * s_parent + (1-w_i)*SCALE*noise_i.
// Outputs fp32 flat: samples (8192x4095), ms (8192x4094), scales (8192x4094),
// columns in reverse level order; root = samples col 4094.
// Column identity: parent_col = (child_col >> 1) + 2048.
//
// r4 structure: 1 row / 256-thread block. ALL row noise prefetched into
// registers at block start (levels 1..7 land on thread tid = tree index;
// levels 8..11 are 1/2/4/8 per thread). Outputs stored scalar-coalesced
// DURING the level walk; barriers are lgkm-only (raw s_barrier, no vmcnt
// drain) so global stores stay in flight across all 11 levels.

constexpr int   kRows  = 8192;
constexpr float kScale = 0.1f;

// Column-ordered (w, sc) table. Zero-init BSS; rewritten every launch.
__device__ __align__(16) float2 g_tab[4096];

__global__ __launch_bounds__(256) void lgt_precompute(
    const float* __restrict__ weights)
{
    int t = blockIdx.x * 256 + threadIdx.x;      // tree index 0..4093
    if (t < 4094) {
        int d = 31 - __clz(t + 2);               // level of node t
        int c = t + 4098 - 3 * (1 << d);         // output column
        float w = 1.0f / (1.0f + __expf(-weights[t]));
        g_tab[c] = make_float2(w, (1.0f - w) * kScale);
    }
}

// Barrier that does NOT drain vmcnt: LDS visibility only (lgkmcnt), so
// global stores/loads issued before it remain in flight.
__device__ __forceinline__ void lgkm_barrier() {
    __builtin_amdgcn_sched_barrier(0);
    asm volatile("s_waitcnt lgkmcnt(0)" ::: "memory");
    __builtin_amdgcn_s_barrier();
    __builtin_amdgcn_sched_barrier(0);
}

__global__ __launch_bounds__(256) void lgt_main(
    const float* __restrict__ noise_root,
    const float* __restrict__ noise_rest,
    float* __restrict__ samples,
    float* __restrict__ ms,
    float* __restrict__ scales)
{
    __shared__ float s[4096];                    // samples, column-ordered

    const int row = blockIdx.x;
    const int tid = threadIdx.x;
    const float* __restrict__ nr = noise_rest + (size_t)row * 4094;
    float* __restrict__ sr = samples + (size_t)row * 4095;
    float* __restrict__ mr = ms      + (size_t)row * 4094;
    float* __restrict__ cr = scales  + (size_t)row * 4094;

    // ---- prefetch the whole row's noise (16 regs), one latency for all ----
    const float nzs = nr[tid];                   // levels 1..7: tree idx == tid
    const float nz8 = nr[254 + tid];             // level 8
    float nz9[2], nz10[4], nz11[8];
    #pragma unroll
    for (int k = 0; k < 2; ++k) nz9[k]  = nr[510  + tid + (k << 8)];
    #pragma unroll
    for (int k = 0; k < 4; ++k) nz10[k] = nr[1022 + tid + (k << 8)];
    #pragma unroll
    for (int k = 0; k < 8; ++k) nz11[k] = nr[2046 + tid + (k << 8)];
    const float rootv = noise_root[row];         // IN_SCALE == 1.0

    if (tid == 0) { s[4094] = rootv; sr[4094] = rootv; }
    lgkm_barrier();

    // ---- levels 1..7: thread t owns tree index t (t in [2^d-2, 2^(d+1)-2)) --
    #pragma unroll
    for (int d = 1; d <= 7; ++d) {
        const int off = (1 << d) - 2;
        const int n   = 1 << d;
        const int colbase = 4096 - (n << 1);
        if (tid >= off && tid < off + n) {
            const int c = colbase + (tid - off);
            const float2 t2 = g_tab[c];
            const float  p  = s[(c >> 1) + 2048];
            const float  mv = t2.x * p;
            const float  v  = fmaf(t2.y, nzs, mv);
            s[c] = v;
            sr[c] = v; mr[c] = mv; cr[c] = t2.y;
        }
        lgkm_barrier();
    }

    // ---- level 8: 256 elements, 1/thread ----
    {
        const int c = 3584 + tid;
        const float2 t2 = g_tab[c];
        const float  p  = s[(c >> 1) + 2048];
        const float  mv = t2.x * p;
        const float  v  = fmaf(t2.y, nz8, mv);
        s[c] = v;
        sr[c] = v; mr[c] = mv; cr[c] = t2.y;
    }
    lgkm_barrier();

    // ---- level 9: 512 elements, 2/thread ----
    #pragma unroll
    for (int k = 0; k < 2; ++k) {
        const int c = 3072 + tid + (k << 8);
        const float2 t2 = g_tab[c];
        const float  p  = s[(c >> 1) + 2048];
        const float  mv = t2.x * p;
        const float  v  = fmaf(t2.y, nz9[k], mv);
        s[c] = v;
        sr[c] = v; mr[c] = mv; cr[c] = t2.y;
    }
    lgkm_barrier();

    // ---- level 10: 1024 elements, 4/thread ----
    #pragma unroll
    for (int k = 0; k < 4; ++k) {
        const int c = 2048 + tid + (k << 8);
        const float2 t2 = g_tab[c];
        const float  p  = s[(c >> 1) + 2048];
        const float  mv = t2.x * p;
        const float  v  = fmaf(t2.y, nz10[k], mv);
        s[c] = v;
        sr[c] = v; mr[c] = mv; cr[c] = t2.y;
    }
    lgkm_barrier();

    // ---- level 11: 2048 elements, 8/thread (no trailing barrier) ----
    #pragma unroll
    for (int k = 0; k < 8; ++k) {
        const int c = tid + (k << 8);
        const float2 t2 = g_tab[c];
        const float  p  = s[(c >> 1) + 2048];
        const float  mv = t2.x * p;
        const float  v  = fmaf(t2.y, nz11[k], mv);
        sr[c] = v; mr[c] = mv; cr[c] = t2.y;     // leaves: no LDS write needed
    }
}

extern "C" void kernel_launch(void* const* d_in, const int* in_sizes, int n_in,
                              void* d_out, int out_size, void* d_ws, size_t ws_size,
                              hipStream_t stream)
{
    const float* weights    = (const float*)d_in[0];
    const float* noise_root = (const float*)d_in[1];
    const float* noise_rest = (const float*)d_in[2];

    float* out     = (float*)d_out;
    float* samples = out;
    float* ms      = samples + (size_t)kRows * 4095;
    float* scales  = ms      + (size_t)kRows * 4094;

    lgt_precompute<<<(4094 + 255) / 256, 256, 0, stream>>>(weights);
    lgt_main<<<kRows, 256, 0, stream>>>(noise_root, noise_rest,
                                        samples, ms, scales);
}

// Round 5
// 120.373 us; speedup vs baseline: 1.2652x; 1.0130x over previous
//
#include <hip/hip_runtime.h>

// LinearGaussianTree, MI355X. 8192 rows; per row a 4095-node binary tree:
// s_i = w_i * s_parent + (1-w_i)*SCALE*noise_i. Outputs fp32 flat:
// samples (8192x4095), ms (8192x4094), scales (8192x4094), reverse level
// order; root = samples col 4094. Column identity: parent = (c>>1)+2048.
//
// r5: levels 1..7 (254 nodes) cooperatively in LDS with lgkm-only barriers;
// levels 8..11 as per-thread SUBTREES (thread t owns level-8 node t and its
// 2+4+8 descendants): zero barriers, zero LDS, contiguous per-thread columns
// -> dwordx2/x4 stores, float4 table loads, float2 noise loads.

constexpr int   kRows  = 8192;
constexpr float kScale = 0.1f;

typedef float f4_ __attribute__((ext_vector_type(4)));
typedef float f2_ __attribute__((ext_vector_type(2)));
typedef f4_ f4u __attribute__((aligned(4)));   // 16B vector at 4B alignment
typedef f2_ f2u __attribute__((aligned(4)));

// Column-ordered (w, sc) table. Zero-init BSS; rewritten every launch.
__device__ __align__(16) float2 g_tab[4096];

__global__ __launch_bounds__(256) void lgt_precompute(
    const float* __restrict__ weights)
{
    int t = blockIdx.x * 256 + threadIdx.x;      // tree index 0..4093
    if (t < 4094) {
        int d = 31 - __clz(t + 2);               // level of node t
        int c = t + 4098 - 3 * (1 << d);         // output column
        float w = 1.0f / (1.0f + __expf(-weights[t]));
        g_tab[c] = make_float2(w, (1.0f - w) * kScale);
    }
}

// Barrier that does NOT drain vmcnt: LDS visibility only, so global
// stores/loads issued before it remain in flight.
__device__ __forceinline__ void lgkm_barrier() {
    __builtin_amdgcn_sched_barrier(0);
    asm volatile("s_waitcnt lgkmcnt(0)" ::: "memory");
    __builtin_amdgcn_s_barrier();
    __builtin_amdgcn_sched_barrier(0);
}

__global__ __launch_bounds__(256) void lgt_main(
    const float* __restrict__ noise_root,
    const float* __restrict__ noise_rest,
    float* __restrict__ samples,
    float* __restrict__ ms,
    float* __restrict__ scales)
{
    __shared__ float sL[256];                    // cols 3840..4095 (root @254)

    const int row = blockIdx.x;
    const int tid = threadIdx.x;
    const float* __restrict__ nr = noise_rest + (size_t)row * 4094;
    float* __restrict__ sr = samples + (size_t)row * 4095;
    float* __restrict__ mr = ms      + (size_t)row * 4094;
    float* __restrict__ cr = scales  + (size_t)row * 4094;

    // ---- prefetch all of this row's noise (one latency for everything) ----
    // nr is 8B-aligned (base 16B + row*16376), all f2_ offsets even.
    const float nzs = nr[tid];                   // levels 1..7: tree idx == tid
    const float n8  = nr[254 + tid];             // level 8 (node tid)
    const f2_  n9   = *(const f2_*)(nr + 510 + 2 * tid);
    const f2_  nA0  = *(const f2_*)(nr + 1022 + 4 * tid);
    const f2_  nA1  = *(const f2_*)(nr + 1022 + 4 * tid + 2);
    f2_ nL[4];
    #pragma unroll
    for (int k = 0; k < 4; ++k)
        nL[k] = *(const f2_*)(nr + 2046 + 8 * tid + 2 * k);
    const float rootv = noise_root[row];         // IN_SCALE == 1.0

    if (tid == 0) { sL[254] = rootv; sr[4094] = rootv; }
    lgkm_barrier();

    // ---- phase A: levels 1..7 in LDS (254 nodes, 8 lgkm barriers) ----
    #pragma unroll
    for (int d = 1; d <= 7; ++d) {
        const int off     = (1 << d) - 2;
        const int n       = 1 << d;
        const int colbase = 4096 - (n << 1);
        if (tid >= off && tid < off + n) {
            const int c = colbase + (tid - off);
            const float2 t2 = g_tab[c];
            const float  p  = sL[(c >> 1) - 1792];   // parent col - 3840
            const float  mv = t2.x * p;
            const float  v  = fmaf(t2.y, nzs, mv);
            sL[c - 3840] = v;
            sr[c] = v; mr[c] = mv; cr[c] = t2.y;
        }
        lgkm_barrier();
    }

    // ---- phase B: per-thread subtree, barrier-free ----
    const float a7 = sL[tid >> 1];               // level-7 ancestor (broadcast)

    // level 8: node tid, col 3584+tid
    const float2 t8 = g_tab[3584 + tid];
    const float  m8 = t8.x * a7;
    const float  v8 = fmaf(t8.y, n8, m8);
    sr[3584 + tid] = v8; mr[3584 + tid] = m8; cr[3584 + tid] = t8.y;

    // level 9: nodes 2t,2t+1 -> cols 3072+2t (contiguous 2)
    const f4_ t9 = *(const f4_*)(&g_tab[3072 + 2 * tid]);   // 16B-aligned
    const float m90 = t9.x * v8, m91 = t9.z * v8;
    const float v90 = fmaf(t9.y, n9.x, m90);
    const float v91 = fmaf(t9.w, n9.y, m91);
    {
        f2_ sv; sv.x = v90; sv.y = v91;
        f2_ mv; mv.x = m90; mv.y = m91;
        f2_ cv; cv.x = t9.y; cv.y = t9.w;
        *(f2u*)(sr + 3072 + 2 * tid) = sv;       // row base only 4B-aligned
        *(f2_*)(mr + 3072 + 2 * tid) = mv;       // even flat idx: 8B-aligned
        *(f2_*)(cr + 3072 + 2 * tid) = cv;
    }

    // level 10: nodes 4t..4t+3 -> cols 2048+4t (contiguous 4)
    const f4_ tA = *(const f4_*)(&g_tab[2048 + 4 * tid]);
    const f4_ tB = *(const f4_*)(&g_tab[2048 + 4 * tid + 2]);
    const float mA0 = tA.x * v90, mA1 = tA.z * v90;
    const float mB0 = tB.x * v91, mB1 = tB.z * v91;
    const float vA0 = fmaf(tA.y, nA0.x, mA0);
    const float vA1 = fmaf(tA.w, nA0.y, mA1);
    const float vB0 = fmaf(tB.y, nA1.x, mB0);
    const float vB1 = fmaf(tB.w, nA1.y, mB1);
    {
        f4_ sv; sv.x = vA0; sv.y = vA1; sv.z = vB0; sv.w = vB1;
        f4_ mv; mv.x = mA0; mv.y = mA1; mv.z = mB0; mv.w = mB1;
        f4_ cv; cv.x = tA.y; cv.y = tA.w; cv.z = tB.y; cv.w = tB.w;
        *(f4u*)(sr + 2048 + 4 * tid) = sv;
        *(f4u*)(mr + 2048 + 4 * tid) = mv;
        *(f4u*)(cr + 2048 + 4 * tid) = cv;
    }

    // level 11: nodes 8t..8t+7 -> cols 8t (contiguous 8)
    const float pv0 = vA0, pv1 = vA1, pv2 = vB0, pv3 = vB1;
    float sv[8], mv[8], cv[8];
    #pragma unroll
    for (int k = 0; k < 4; ++k) {
        const f4_  t = *(const f4_*)(&g_tab[8 * tid + 2 * k]);  // 16B-aligned
        const float p = (k == 0) ? pv0 : (k == 1) ? pv1 : (k == 2) ? pv2 : pv3;
        const float m0 = t.x * p, m1 = t.z * p;
        sv[2 * k]     = fmaf(t.y, nL[k].x, m0);
        sv[2 * k + 1] = fmaf(t.w, nL[k].y, m1);
        mv[2 * k] = m0; mv[2 * k + 1] = m1;
        cv[2 * k] = t.y; cv[2 * k + 1] = t.w;
    }
    {
        f4_ a, b;
        a.x = sv[0]; a.y = sv[1]; a.z = sv[2]; a.w = sv[3];
        b.x = sv[4]; b.y = sv[5]; b.z = sv[6]; b.w = sv[7];
        *(f4u*)(sr + 8 * tid)     = a;
        *(f4u*)(sr + 8 * tid + 4) = b;
        a.x = mv[0]; a.y = mv[1]; a.z = mv[2]; a.w = mv[3];
        b.x = mv[4]; b.y = mv[5]; b.z = mv[6]; b.w = mv[7];
        *(f4u*)(mr + 8 * tid)     = a;
        *(f4u*)(mr + 8 * tid + 4) = b;
        a.x = cv[0]; a.y = cv[1]; a.z = cv[2]; a.w = cv[3];
        b.x = cv[4]; b.y = cv[5]; b.z = cv[6]; b.w = cv[7];
        *(f4u*)(cr + 8 * tid)     = a;
        *(f4u*)(cr + 8 * tid + 4) = b;
    }
}

extern "C" void kernel_launch(void* const* d_in, const int* in_sizes, int n_in,
                              void* d_out, int out_size, void* d_ws, size_t ws_size,
                              hipStream_t stream)
{
    const float* weights    = (const float*)d_in[0];
    const float* noise_root = (const float*)d_in[1];
    const float* noise_rest = (const float*)d_in[2];

    float* out     = (float*)d_out;
    float* samples = out;
    float* ms      = samples + (size_t)kRows * 4095;
    float* scales  = ms      + (size_t)kRows * 4094;

    lgt_precompute<<<(4094 + 255) / 256, 256, 0, stream>>>(weights);
    lgt_main<<<kRows, 256, 0, stream>>>(noise_root, noise_rest,
                                        samples, ms, scales);
}